// Round 12
// baseline (482.400 us; speedup 1.0000x reference)
//
#include <hip/hip_runtime.h>
#include <hip/hip_bf16.h>

#define NB 16     // batch
#define NN 512    // nodes
#define NF 64     // F_in == F_out
#define NE 16     // emb dim
#define NKF 192   // K*F_in
#define NNODE (NB*NN)   // 8192
#define GRID 512  // 2 blocks/CU co-resident (LDS 25KB x2, VGPR<=256 via launch_bounds)

typedef __hip_bfloat16 bf16;
typedef __attribute__((ext_vector_type(8))) short short8;
typedef __attribute__((ext_vector_type(4))) float f32x4;

typedef const __attribute__((address_space(1))) char gchar;
typedef __attribute__((address_space(3))) char lchar;

__device__ inline void gload16(const void* g, void* l) {
    __builtin_amdgcn_global_load_lds((gchar*)g, (lchar*)l, 16, 0, 0);
}

__device__ inline short f2bs(float f) {
    union { bf16 b; short s; } u; u.b = __float2bfloat16(f); return u.s;
}

// ---- software grid barrier (R11-verified) ---------------------------------
__device__ __forceinline__ void gbar(unsigned* cnt, int nb) {
    __syncthreads();
    if (threadIdx.x == 0) {
        __threadfence();
        __hip_atomic_fetch_add(cnt, 1u, __ATOMIC_RELEASE, __HIP_MEMORY_SCOPE_AGENT);
        while (__hip_atomic_load(cnt, __ATOMIC_ACQUIRE, __HIP_MEMORY_SCOPE_AGENT)
               < (unsigned)nb)
            __builtin_amdgcn_s_sleep(1);
        __threadfence();
    }
    __syncthreads();
}

// ---- spmm unit (R9/R11-verified body): C = Ah_b[n0:n0+64][:] @ Bsrc_b^T ---
template <int PASS>
__device__ __forceinline__ void spmm_unit(
    char* smem, int tid, int lane, int w, int n0, int b,
    const short* __restrict__ AhS, const short* __restrict__ Bsrc,
    const float* __restrict__ x, bf16* __restrict__ xg, bf16* __restrict__ y1T)
{
    short* As = (short*)smem;
    short* Xs = (short*)(smem + 4096);
    float (*Cs)[66] = (float (*)[66])(smem + 8192);
    const short* Ab = AhS + (size_t)b * NN * NN;
    const short* Xb = Bsrc + (size_t)b * NF * NN;

    int sr = tid >> 2;
    int p  = tid & 3;
    int cA = p ^ ((sr >> 1) & 3);

    int fr = lane & 15;
    int fc = ((lane >> 4) ^ ((fr >> 1) & 3)) * 8;

    f32x4 acc[4] = {};

    for (int kt = 0; kt < 16; ++kt) {
        __syncthreads();
        gload16(Ab + (size_t)(n0 + sr) * NN + kt * 32 + cA * 8, As + tid * 8);
        gload16(Xb + (size_t)sr * NN + kt * 32 + cA * 8, Xs + tid * 8);
        __syncthreads();
        short8 afr = *(const short8*)&As[(16 * w + fr) * 32 + fc];
        #pragma unroll
        for (int j = 0; j < 4; ++j) {
            short8 bfr = *(const short8*)&Xs[(16 * j + fr) * 32 + fc];
            acc[j] = __builtin_amdgcn_mfma_f32_16x16x32_bf16(afr, bfr, acc[j], 0, 0, 0);
        }
    }

    #pragma unroll
    for (int j = 0; j < 4; ++j)
        #pragma unroll
        for (int r = 0; r < 4; ++r)
            Cs[16 * w + 4 * (lane >> 4) + r][16 * j + (lane & 15)] = acc[j][r];
    __syncthreads();

    int nl = tid >> 2, f0 = (tid & 3) * 16;
    size_t node = (size_t)b * NN + n0 + nl;
    float cv[16];
    #pragma unroll
    for (int i = 0; i < 16; ++i) cv[i] = Cs[nl][f0 + i];
    if (PASS == 0) {
        short8 p0, p1;
        #pragma unroll
        for (int i = 0; i < 8; ++i) { p0[i] = f2bs(cv[i]); p1[i] = f2bs(cv[8 + i]); }
        *(short8*)&xg[node * NKF + 64 + f0] = p0;
        *(short8*)&xg[node * NKF + 64 + f0 + 8] = p1;
        int f = tid >> 2, nq0 = (tid & 3) * 16;
        bf16* yt = y1T + (size_t)(b * NF + f) * NN + n0 + nq0;
        #pragma unroll
        for (int h = 0; h < 2; ++h) {
            short8 o;
            #pragma unroll
            for (int i = 0; i < 8; ++i) o[i] = f2bs(Cs[nq0 + h * 8 + i][f]);
            *(short8*)&yt[h * 8] = o;
        }
    } else {
        const float* xp = x + node * NF + f0;
        short8 p0, p1;
        #pragma unroll
        for (int i = 0; i < 8; ++i) {
            p0[i] = f2bs(2.f * cv[i] - xp[i]);
            p1[i] = f2bs(2.f * cv[8 + i] - xp[8 + i]);
        }
        *(short8*)&xg[node * NKF + 128 + f0] = p0;
        *(short8*)&xg[node * NKF + 128 + f0 + 8] = p1;
    }
    __syncthreads();
}

// =================== mega kernel: 6 phases, 5 soft grid syncs ==============
__global__ __launch_bounds__(256, 2) void k_mega(
    const float* __restrict__ A, const float* __restrict__ x,
    const float* __restrict__ Wp, const float* __restrict__ emb,
    const float* __restrict__ bpool, float* __restrict__ dis,
    bf16* __restrict__ xg, bf16* __restrict__ xT, bf16* __restrict__ y1T,
    bf16* __restrict__ Bt, bf16* __restrict__ Ah, bf16* __restrict__ t,
    float* __restrict__ out, unsigned* __restrict__ cnt)
{
    __shared__ __attribute__((aligned(16))) char smem[25088];
    int tid = threadIdx.x, lane = tid & 63, w = tid >> 6;
    int nb = gridDim.x;

    // ---------------- Phase A: dis = rsqrt(rowsum(relu A)+1), float4 --------
    for (int u = blockIdx.x; u < 2048; u += nb) {
        int row = u * 4 + w;
        const float4* a = (const float4*)(A + (size_t)row * NN);
        float s = 0.f;
        #pragma unroll
        for (int j = 0; j < 2; ++j) {
            float4 v = a[lane + 64 * j];
            s += fmaxf(v.x, 0.f) + fmaxf(v.y, 0.f) + fmaxf(v.z, 0.f) + fmaxf(v.w, 0.f);
        }
        #pragma unroll
        for (int off = 32; off >= 1; off >>= 1) s += __shfl_down(s, off, 64);
        if (lane == 0) dis[row] = rsqrtf(fmaxf(s + 1.0f, 1e-6f));
    }
    gbar(cnt + 0, nb);

    // ---------------- Phase B: ahat (2048) + xpack/xT (128) + wcvt (48) -----
    {
        float (*Ts)[66] = (float (*)[66])smem;
        for (int u = blockIdx.x; u < 2224; u += nb) {
            if (u < 2048) {
                int row = u * 4 + w;
                int m0 = lane * 8;
                int b = row >> 9, n = row & (NN - 1);
                const float* db = dis + b * NN;
                float dn = db[n];
                const float* ap = A + (size_t)row * NN + m0;
                float4 a0 = *(const float4*)ap, a1 = *(const float4*)(ap + 4);
                float4 d0 = *(const float4*)(db + m0), d1 = *(const float4*)(db + m0 + 4);
                float av[8] = {a0.x, a0.y, a0.z, a0.w, a1.x, a1.y, a1.z, a1.w};
                float dm[8] = {d0.x, d0.y, d0.z, d0.w, d1.x, d1.y, d1.z, d1.w};
                short8 o;
                #pragma unroll
                for (int i = 0; i < 8; ++i) {
                    float v = fmaxf(av[i], 0.f) + ((n == m0 + i) ? 1.f : 0.f);
                    o[i] = f2bs(v * dn * dm[i]);
                }
                *(short8*)&Ah[(size_t)row * NN + m0] = o;
            } else if (u < 2176) {
                int node0 = (u - 2048) * 64;
                int r = tid >> 2, f0 = (tid & 3) * 16;
                const float* xp = x + (size_t)(node0 + r) * NF + f0;
                float v[16];
                #pragma unroll
                for (int i = 0; i < 16; ++i) v[i] = xp[i];
                short8 p0, p1;
                #pragma unroll
                for (int i = 0; i < 8; ++i) { p0[i] = f2bs(v[i]); p1[i] = f2bs(v[8 + i]); }
                *(short8*)&xg[(size_t)(node0 + r) * NKF + f0] = p0;
                *(short8*)&xg[(size_t)(node0 + r) * NKF + f0 + 8] = p1;
                #pragma unroll
                for (int i = 0; i < 4; ++i)
                    *(float4*)&Ts[r][f0 + i * 4] = *(const float4*)(v + i * 4);
                __syncthreads();
                int f = tid >> 2, nq0 = (tid & 3) * 16;
                int b = node0 >> 9, nloc = node0 & (NN - 1);
                bf16* xt = xT + (size_t)(b * NF + f) * NN + nloc + nq0;
                #pragma unroll
                for (int h = 0; h < 2; ++h) {
                    short8 o;
                    #pragma unroll
                    for (int i = 0; i < 8; ++i) o[i] = f2bs(Ts[nq0 + h * 8 + i][f]);
                    *(short8*)&xt[h * 8] = o;
                }
                __syncthreads();
            } else {
                int q = u - 2176;
                int e = q / 3, kt = q % 3;
                int r = tid >> 2, o0 = (tid & 3) * 16;
                const float* wp = Wp + (size_t)e * (NKF * NF) + (size_t)(kt * 64 + r) * NF + o0;
                #pragma unroll
                for (int i = 0; i < 4; ++i)
                    *(float4*)&Ts[r][o0 + i * 4] = *(const float4*)(wp + i * 4);
                __syncthreads();
                int o = tid >> 2, r0 = (tid & 3) * 16;
                bf16* bt = Bt + (size_t)(e * 64 + o) * NKF + kt * 64 + r0;
                #pragma unroll
                for (int h = 0; h < 2; ++h) {
                    short8 wv;
                    #pragma unroll
                    for (int i = 0; i < 8; ++i) wv[i] = f2bs(Ts[r0 + h * 8 + i][o]);
                    *(short8*)&bt[h * 8] = wv;
                }
                __syncthreads();
            }
        }
    }
    gbar(cnt + 1, nb);

    // ---------------- Phase C: spmm0 (y1) -----------------------------------
    for (int u = blockIdx.x; u < 128; u += nb)
        spmm_unit<0>(smem, tid, lane, w, (u & 7) * 64, u >> 3,
                     (const short*)Ah, (const short*)xT, x, xg, y1T);
    gbar(cnt + 2, nb);

    // ---------------- Phase D: spmm1 (y2) -----------------------------------
    for (int u = blockIdx.x; u < 128; u += nb)
        spmm_unit<1>(smem, tid, lane, w, (u & 7) * 64, u >> 3,
                     (const short*)Ah, (const short*)y1T, x, xg, y1T);
    gbar(cnt + 3, nb);

    // ---------------- Phase E: gemm t = Xg @ Bt^T (R7-verified body) --------
    {
        short* As = (short*)smem;           // 8192 B
        short* Bs = (short*)(smem + 8192);  // 8192 B
        const short* xgs = (const short*)xg;
        const short* Bts = (const short*)Bt;
        for (int u = blockIdx.x; u < 512; u += nb) {
            int n0 = (u & 63) * 128;
            int c0 = (u >> 6) * 128;

            int rA0 = tid >> 2;
            int p   = tid & 3;
            int cA  = p ^ ((rA0 >> 1) & 3);

            int fr = lane & 15;
            int fc = ((lane >> 4) ^ ((fr >> 1) & 3)) * 8;

            f32x4 acc[4][4] = {};

            for (int kt = 0; kt < 6; ++kt) {
                __syncthreads();
                gload16(xgs + (size_t)(n0 + rA0) * NKF + kt * 32 + cA * 8, As + tid * 8);
                gload16(xgs + (size_t)(n0 + rA0 + 64) * NKF + kt * 32 + cA * 8, As + 2048 + tid * 8);
                gload16(Bts + (size_t)(c0 + rA0) * NKF + kt * 32 + cA * 8, Bs + tid * 8);
                gload16(Bts + (size_t)(c0 + rA0 + 64) * NKF + kt * 32 + cA * 8, Bs + 2048 + tid * 8);
                __syncthreads();

                int wr = w >> 1, wc = w & 1;
                short8 a[4], bfr[4];
                #pragma unroll
                for (int i = 0; i < 4; ++i)
                    a[i] = *(const short8*)&As[(wr * 64 + i * 16 + fr) * 32 + fc];
                #pragma unroll
                for (int j = 0; j < 4; ++j)
                    bfr[j] = *(const short8*)&Bs[(wc * 64 + j * 16 + fr) * 32 + fc];
                #pragma unroll
                for (int i = 0; i < 4; ++i)
                    #pragma unroll
                    for (int j = 0; j < 4; ++j)
                        acc[i][j] = __builtin_amdgcn_mfma_f32_16x16x32_bf16(a[i], bfr[j], acc[i][j], 0, 0, 0);
            }

            int wr = w >> 1, wc = w & 1;
            #pragma unroll
            for (int i = 0; i < 4; ++i)
                #pragma unroll
                for (int j = 0; j < 4; ++j)
                    #pragma unroll
                    for (int r = 0; r < 4; ++r) {
                        int m = n0 + wr * 64 + i * 16 + (lane >> 4) * 4 + r;
                        int cc = c0 + wc * 64 + j * 16 + (lane & 15);
                        t[(size_t)m * 1024 + cc] = __float2bfloat16(acc[i][j][r]);
                    }
            __syncthreads();
        }
    }
    gbar(cnt + 4, nb);

    // ---------------- Phase F: reduce (R7-verified body) --------------------
    for (int u = blockIdx.x; u < 2048; u += nb) {
        int gid = u * 256 + tid;
        int node = gid >> 6, o = gid & 63;
        float s = 0.f;
        #pragma unroll
        for (int e = 0; e < NE; ++e) {
            float tv = __bfloat162float(t[(size_t)node * 1024 + e * 64 + o]);
            s = fmaf(emb[(size_t)node * NE + e], tv + bpool[e * 64 + o], s);
        }
        out[gid] = s;
    }
}

extern "C" void kernel_launch(void* const* d_in, const int* in_sizes, int n_in,
                              void* d_out, int out_size, void* d_ws, size_t ws_size,
                              hipStream_t stream) {
    const float* x    = (const float*)d_in[0];   // [16,512,64]
    const float* emb  = (const float*)d_in[1];   // [16,512,16]
    const float* Aad  = (const float*)d_in[2];   // [16,512,512]
    const float* Wp   = (const float*)d_in[3];   // [16,3,64,64]
    const float* bp   = (const float*)d_in[4];   // [16,64]
    float* out = (float*)d_out;                  // [16,512,64]

    float* ws  = (float*)d_ws;
    float* dis = ws;                                  // 8192 f32
    bf16*  xT  = (bf16*)(ws + 8192);                  // 16*64*512 bf16
    bf16*  y1T = (bf16*)(ws + 270336);                // same
    bf16*  xg  = (bf16*)(ws + 532480);                // 8192*192 bf16
    bf16*  Bt  = (bf16*)(ws + 1318912);               // 1024*192 bf16
    bf16*  Ah  = (bf16*)(ws + 1417216);               // 16*512*512 bf16
    bf16*  t   = (bf16*)(ws + 3514368);               // 8192*1024 bf16
    unsigned* cnt = (unsigned*)(ws + 7708672);        // 5 barrier counters
    // ws end: 30.8 MB + 20 B

    hipMemsetAsync((void*)cnt, 0, 5 * sizeof(unsigned), stream);
    k_mega<<<GRID, 256, 0, stream>>>(Aad, x, Wp, emb, bp, dis,
                                     xg, xT, y1T, Bt, Ah, t, out, cnt);
}

// Round 13
// 235.830 us; speedup vs baseline: 2.0455x; 2.0455x over previous
//
#include <hip/hip_runtime.h>
#include <hip/hip_bf16.h>

#define NB 16     // batch
#define NN 512    // nodes
#define NF 64     // F_in == F_out
#define NE 16     // emb dim
#define NKF 192   // K*F_in
#define NNODE (NB*NN)   // 8192
#define GRID 512  // 2 blocks/CU co-resident (verified resident in R12)

typedef __hip_bfloat16 bf16;
typedef __attribute__((ext_vector_type(8))) short short8;
typedef __attribute__((ext_vector_type(4))) float f32x4;

typedef const __attribute__((address_space(1))) char gchar;
typedef __attribute__((address_space(3))) char lchar;

__device__ inline void gload16(const void* g, void* l) {
    __builtin_amdgcn_global_load_lds((gchar*)g, (lchar*)l, 16, 0, 0);
}

__device__ inline short f2bs(float f) {
    union { bf16 b; short s; } u; u.b = __float2bfloat16(f); return u.s;
}

// ---- software grid barrier, cheap-spin version ----------------------------
// R12's version spun on ACQUIRE loads + 2x __threadfence -> per-poll cache
// invalidates at agent scope = the 460us storm. Fix: ACQ_REL on arrival
// (releases prior writes), RELAXED polling (no side effects), ONE acquire
// load after exit (single invalidate so we see remote writes).
__device__ __forceinline__ void gbar(unsigned* cnt, int nb) {
    __syncthreads();
    if (threadIdx.x == 0) {
        __hip_atomic_fetch_add(cnt, 1u, __ATOMIC_ACQ_REL, __HIP_MEMORY_SCOPE_AGENT);
        while (__hip_atomic_load(cnt, __ATOMIC_RELAXED, __HIP_MEMORY_SCOPE_AGENT)
               < (unsigned)nb)
            __builtin_amdgcn_s_sleep(2);
        (void)__hip_atomic_load(cnt, __ATOMIC_ACQUIRE, __HIP_MEMORY_SCOPE_AGENT);
    }
    __syncthreads();
}

// ---- spmm unit (R9/R11/R12-verified body) ---------------------------------
template <int PASS>
__device__ __forceinline__ void spmm_unit(
    char* smem, int tid, int lane, int w, int n0, int b,
    const short* __restrict__ AhS, const short* __restrict__ Bsrc,
    const float* __restrict__ x, bf16* __restrict__ xg, bf16* __restrict__ y1T)
{
    short* As = (short*)smem;
    short* Xs = (short*)(smem + 4096);
    float (*Cs)[66] = (float (*)[66])(smem + 8192);
    const short* Ab = AhS + (size_t)b * NN * NN;
    const short* Xb = Bsrc + (size_t)b * NF * NN;

    int sr = tid >> 2;
    int p  = tid & 3;
    int cA = p ^ ((sr >> 1) & 3);

    int fr = lane & 15;
    int fc = ((lane >> 4) ^ ((fr >> 1) & 3)) * 8;

    f32x4 acc[4] = {};

    for (int kt = 0; kt < 16; ++kt) {
        __syncthreads();
        gload16(Ab + (size_t)(n0 + sr) * NN + kt * 32 + cA * 8, As + tid * 8);
        gload16(Xb + (size_t)sr * NN + kt * 32 + cA * 8, Xs + tid * 8);
        __syncthreads();
        short8 afr = *(const short8*)&As[(16 * w + fr) * 32 + fc];
        #pragma unroll
        for (int j = 0; j < 4; ++j) {
            short8 bfr = *(const short8*)&Xs[(16 * j + fr) * 32 + fc];
            acc[j] = __builtin_amdgcn_mfma_f32_16x16x32_bf16(afr, bfr, acc[j], 0, 0, 0);
        }
    }

    #pragma unroll
    for (int j = 0; j < 4; ++j)
        #pragma unroll
        for (int r = 0; r < 4; ++r)
            Cs[16 * w + 4 * (lane >> 4) + r][16 * j + (lane & 15)] = acc[j][r];
    __syncthreads();

    int nl = tid >> 2, f0 = (tid & 3) * 16;
    size_t node = (size_t)b * NN + n0 + nl;
    float cv[16];
    #pragma unroll
    for (int i = 0; i < 16; ++i) cv[i] = Cs[nl][f0 + i];
    if (PASS == 0) {
        short8 p0, p1;
        #pragma unroll
        for (int i = 0; i < 8; ++i) { p0[i] = f2bs(cv[i]); p1[i] = f2bs(cv[8 + i]); }
        *(short8*)&xg[node * NKF + 64 + f0] = p0;
        *(short8*)&xg[node * NKF + 64 + f0 + 8] = p1;
        int f = tid >> 2, nq0 = (tid & 3) * 16;
        bf16* yt = y1T + (size_t)(b * NF + f) * NN + n0 + nq0;
        #pragma unroll
        for (int h = 0; h < 2; ++h) {
            short8 o;
            #pragma unroll
            for (int i = 0; i < 8; ++i) o[i] = f2bs(Cs[nq0 + h * 8 + i][f]);
            *(short8*)&yt[h * 8] = o;
        }
    } else {
        const float* xp = x + node * NF + f0;
        short8 p0, p1;
        #pragma unroll
        for (int i = 0; i < 8; ++i) {
            p0[i] = f2bs(2.f * cv[i] - xp[i]);
            p1[i] = f2bs(2.f * cv[8 + i] - xp[8 + i]);
        }
        *(short8*)&xg[node * NKF + 128 + f0] = p0;
        *(short8*)&xg[node * NKF + 128 + f0 + 8] = p1;
    }
    __syncthreads();
}

// =================== mega kernel: 6 phases, 5 soft grid syncs ==============
__global__ __launch_bounds__(256, 2) void k_mega(
    const float* __restrict__ A, const float* __restrict__ x,
    const float* __restrict__ Wp, const float* __restrict__ emb,
    const float* __restrict__ bpool, float* __restrict__ dis,
    bf16* __restrict__ xg, bf16* __restrict__ xT, bf16* __restrict__ y1T,
    bf16* __restrict__ Bt, bf16* __restrict__ Ah, bf16* __restrict__ t,
    float* __restrict__ out, unsigned* __restrict__ cnt)
{
    __shared__ __attribute__((aligned(16))) char smem[25088];
    int tid = threadIdx.x, lane = tid & 63, w = tid >> 6;
    int nb = gridDim.x;

    // ---------------- Phase A: dis = rsqrt(rowsum(relu A)+1), float4 --------
    for (int u = blockIdx.x; u < 2048; u += nb) {
        int row = u * 4 + w;
        const float4* a = (const float4*)(A + (size_t)row * NN);
        float s = 0.f;
        #pragma unroll
        for (int j = 0; j < 2; ++j) {
            float4 v = a[lane + 64 * j];
            s += fmaxf(v.x, 0.f) + fmaxf(v.y, 0.f) + fmaxf(v.z, 0.f) + fmaxf(v.w, 0.f);
        }
        #pragma unroll
        for (int off = 32; off >= 1; off >>= 1) s += __shfl_down(s, off, 64);
        if (lane == 0) dis[row] = rsqrtf(fmaxf(s + 1.0f, 1e-6f));
    }
    gbar(cnt + 0, nb);

    // ---------------- Phase B: ahat (2048) + xpack/xT (128) + wcvt (48) -----
    {
        float (*Ts)[66] = (float (*)[66])smem;
        for (int u = blockIdx.x; u < 2224; u += nb) {
            if (u < 2048) {
                int row = u * 4 + w;
                int m0 = lane * 8;
                int b = row >> 9, n = row & (NN - 1);
                const float* db = dis + b * NN;
                float dn = db[n];
                const float* ap = A + (size_t)row * NN + m0;
                float4 a0 = *(const float4*)ap, a1 = *(const float4*)(ap + 4);
                float4 d0 = *(const float4*)(db + m0), d1 = *(const float4*)(db + m0 + 4);
                float av[8] = {a0.x, a0.y, a0.z, a0.w, a1.x, a1.y, a1.z, a1.w};
                float dm[8] = {d0.x, d0.y, d0.z, d0.w, d1.x, d1.y, d1.z, d1.w};
                short8 o;
                #pragma unroll
                for (int i = 0; i < 8; ++i) {
                    float v = fmaxf(av[i], 0.f) + ((n == m0 + i) ? 1.f : 0.f);
                    o[i] = f2bs(v * dn * dm[i]);
                }
                *(short8*)&Ah[(size_t)row * NN + m0] = o;
            } else if (u < 2176) {
                int node0 = (u - 2048) * 64;
                int r = tid >> 2, f0 = (tid & 3) * 16;
                const float* xp = x + (size_t)(node0 + r) * NF + f0;
                float v[16];
                #pragma unroll
                for (int i = 0; i < 16; ++i) v[i] = xp[i];
                short8 p0, p1;
                #pragma unroll
                for (int i = 0; i < 8; ++i) { p0[i] = f2bs(v[i]); p1[i] = f2bs(v[8 + i]); }
                *(short8*)&xg[(size_t)(node0 + r) * NKF + f0] = p0;
                *(short8*)&xg[(size_t)(node0 + r) * NKF + f0 + 8] = p1;
                #pragma unroll
                for (int i = 0; i < 4; ++i)
                    *(float4*)&Ts[r][f0 + i * 4] = *(const float4*)(v + i * 4);
                __syncthreads();
                int f = tid >> 2, nq0 = (tid & 3) * 16;
                int b = node0 >> 9, nloc = node0 & (NN - 1);
                bf16* xt = xT + (size_t)(b * NF + f) * NN + nloc + nq0;
                #pragma unroll
                for (int h = 0; h < 2; ++h) {
                    short8 o;
                    #pragma unroll
                    for (int i = 0; i < 8; ++i) o[i] = f2bs(Ts[nq0 + h * 8 + i][f]);
                    *(short8*)&xt[h * 8] = o;
                }
                __syncthreads();
            } else {
                int q = u - 2176;
                int e = q / 3, kt = q % 3;
                int r = tid >> 2, o0 = (tid & 3) * 16;
                const float* wp = Wp + (size_t)e * (NKF * NF) + (size_t)(kt * 64 + r) * NF + o0;
                #pragma unroll
                for (int i = 0; i < 4; ++i)
                    *(float4*)&Ts[r][o0 + i * 4] = *(const float4*)(wp + i * 4);
                __syncthreads();
                int o = tid >> 2, r0 = (tid & 3) * 16;
                bf16* bt = Bt + (size_t)(e * 64 + o) * NKF + kt * 64 + r0;
                #pragma unroll
                for (int h = 0; h < 2; ++h) {
                    short8 wv;
                    #pragma unroll
                    for (int i = 0; i < 8; ++i) wv[i] = f2bs(Ts[r0 + h * 8 + i][o]);
                    *(short8*)&bt[h * 8] = wv;
                }
                __syncthreads();
            }
        }
    }
    gbar(cnt + 1, nb);

    // ---------------- Phase C: spmm0 (y1) -----------------------------------
    for (int u = blockIdx.x; u < 128; u += nb)
        spmm_unit<0>(smem, tid, lane, w, (u & 7) * 64, u >> 3,
                     (const short*)Ah, (const short*)xT, x, xg, y1T);
    gbar(cnt + 2, nb);

    // ---------------- Phase D: spmm1 (y2) -----------------------------------
    for (int u = blockIdx.x; u < 128; u += nb)
        spmm_unit<1>(smem, tid, lane, w, (u & 7) * 64, u >> 3,
                     (const short*)Ah, (const short*)y1T, x, xg, y1T);
    gbar(cnt + 3, nb);

    // ---------------- Phase E: gemm t = Xg @ Bt^T (R7-verified body) --------
    {
        short* As = (short*)smem;           // 8192 B
        short* Bs = (short*)(smem + 8192);  // 8192 B
        const short* xgs = (const short*)xg;
        const short* Bts = (const short*)Bt;
        for (int u = blockIdx.x; u < 512; u += nb) {
            int n0 = (u & 63) * 128;
            int c0 = (u >> 6) * 128;

            int rA0 = tid >> 2;
            int p   = tid & 3;
            int cA  = p ^ ((rA0 >> 1) & 3);

            int fr = lane & 15;
            int fc = ((lane >> 4) ^ ((fr >> 1) & 3)) * 8;

            f32x4 acc[4][4] = {};

            for (int kt = 0; kt < 6; ++kt) {
                __syncthreads();
                gload16(xgs + (size_t)(n0 + rA0) * NKF + kt * 32 + cA * 8, As + tid * 8);
                gload16(xgs + (size_t)(n0 + rA0 + 64) * NKF + kt * 32 + cA * 8, As + 2048 + tid * 8);
                gload16(Bts + (size_t)(c0 + rA0) * NKF + kt * 32 + cA * 8, Bs + tid * 8);
                gload16(Bts + (size_t)(c0 + rA0 + 64) * NKF + kt * 32 + cA * 8, Bs + 2048 + tid * 8);
                __syncthreads();

                int wr = w >> 1, wc = w & 1;
                short8 a[4], bfr[4];
                #pragma unroll
                for (int i = 0; i < 4; ++i)
                    a[i] = *(const short8*)&As[(wr * 64 + i * 16 + fr) * 32 + fc];
                #pragma unroll
                for (int j = 0; j < 4; ++j)
                    bfr[j] = *(const short8*)&Bs[(wc * 64 + j * 16 + fr) * 32 + fc];
                #pragma unroll
                for (int i = 0; i < 4; ++i)
                    #pragma unroll
                    for (int j = 0; j < 4; ++j)
                        acc[i][j] = __builtin_amdgcn_mfma_f32_16x16x32_bf16(a[i], bfr[j], acc[i][j], 0, 0, 0);
            }

            int wr = w >> 1, wc = w & 1;
            #pragma unroll
            for (int i = 0; i < 4; ++i)
                #pragma unroll
                for (int j = 0; j < 4; ++j)
                    #pragma unroll
                    for (int r = 0; r < 4; ++r) {
                        int m = n0 + wr * 64 + i * 16 + (lane >> 4) * 4 + r;
                        int cc = c0 + wc * 64 + j * 16 + (lane & 15);
                        t[(size_t)m * 1024 + cc] = __float2bfloat16(acc[i][j][r]);
                    }
            __syncthreads();
        }
    }
    gbar(cnt + 4, nb);

    // ---------------- Phase F: reduce (R7-verified body) --------------------
    for (int u = blockIdx.x; u < 2048; u += nb) {
        int gid = u * 256 + tid;
        int node = gid >> 6, o = gid & 63;
        float s = 0.f;
        #pragma unroll
        for (int e = 0; e < NE; ++e) {
            float tv = __bfloat162float(t[(size_t)node * 1024 + e * 64 + o]);
            s = fmaf(emb[(size_t)node * NE + e], tv + bpool[e * 64 + o], s);
        }
        out[gid] = s;
    }
}

extern "C" void kernel_launch(void* const* d_in, const int* in_sizes, int n_in,
                              void* d_out, int out_size, void* d_ws, size_t ws_size,
                              hipStream_t stream) {
    const float* x    = (const float*)d_in[0];   // [16,512,64]
    const float* emb  = (const float*)d_in[1];   // [16,512,16]
    const float* Aad  = (const float*)d_in[2];   // [16,512,512]
    const float* Wp   = (const float*)d_in[3];   // [16,3,64,64]
    const float* bp   = (const float*)d_in[4];   // [16,64]
    float* out = (float*)d_out;                  // [16,512,64]

    float* ws  = (float*)d_ws;
    float* dis = ws;                                  // 8192 f32
    bf16*  xT  = (bf16*)(ws + 8192);                  // 16*64*512 bf16
    bf16*  y1T = (bf16*)(ws + 270336);                // same
    bf16*  xg  = (bf16*)(ws + 532480);                // 8192*192 bf16
    bf16*  Bt  = (bf16*)(ws + 1318912);               // 1024*192 bf16
    bf16*  Ah  = (bf16*)(ws + 1417216);               // 16*512*512 bf16
    bf16*  t   = (bf16*)(ws + 3514368);               // 8192*1024 bf16
    unsigned* cnt = (unsigned*)(ws + 7708672);        // 5 barrier counters
    // ws end: 30.8 MB + 20 B

    hipMemsetAsync((void*)cnt, 0, 5 * sizeof(unsigned), stream);
    k_mega<<<GRID, 256, 0, stream>>>(Aad, x, Wp, emb, bp, dis,
                                     xg, xT, y1T, Bt, Ah, t, out, cnt);
}

// Round 14
// 42.081 us; speedup vs baseline: 11.4636x; 5.6042x over previous
//
#include <hip/hip_runtime.h>
#include <hip/hip_bf16.h>

#define NB 16     // batch
#define NN 512    // nodes
#define NF 64     // F_in == F_out
#define NE 16     // emb dim
#define NKF 192   // K*F_in
#define NNODE (NB*NN)   // 8192

typedef __hip_bfloat16 bf16;
typedef __attribute__((ext_vector_type(8))) short short8;
typedef __attribute__((ext_vector_type(4))) float f32x4;

typedef const __attribute__((address_space(1))) char gchar;
typedef __attribute__((address_space(3))) char lchar;

__device__ inline void gload16(const void* g, void* l) {
    __builtin_amdgcn_global_load_lds((gchar*)g, (lchar*)l, 16, 0, 0);
}

__device__ inline short f2bs(float f) {
    union { bf16 b; short s; } u; u.b = __float2bfloat16(f); return u.s;
}

// ---------------- k_pre: fused dinv + x(pack+transpose) + wcvt -------------
// blocks [0,2048):     dis[row] = rsqrt(sum_m relu(A[row,m]) + 1)   (float4)
// blocks [2048,2176):  xg[:,0:64] = bf16(x); xT[b][f][n] = bf16(x)^T
// blocks [2176,2224):  Bt[e*64+o][kf] = bf16(Wp[e][kf][o]) via LDS transpose
__global__ __launch_bounds__(256) void k_pre(
    const float* __restrict__ A, const float* __restrict__ x,
    const float* __restrict__ Wp, float* __restrict__ dis,
    bf16* __restrict__ xg, bf16* __restrict__ xT, bf16* __restrict__ Bt) {
    __shared__ float Ts[64][66];
    int bid = blockIdx.x, tid = threadIdx.x;
    if (bid < 2048) {
        int row = bid * 4 + (tid >> 6);
        int lane = tid & 63;
        const float4* a = (const float4*)(A + (size_t)row * NN);
        float s = 0.f;
        #pragma unroll
        for (int j = 0; j < 2; ++j) {
            float4 v = a[lane + 64 * j];
            s += fmaxf(v.x, 0.f) + fmaxf(v.y, 0.f) + fmaxf(v.z, 0.f) + fmaxf(v.w, 0.f);
        }
        #pragma unroll
        for (int off = 32; off >= 1; off >>= 1) s += __shfl_down(s, off, 64);
        if (lane == 0) dis[row] = rsqrtf(fmaxf(s + 1.0f, 1e-6f));
    } else if (bid < 2176) {
        int node0 = (bid - 2048) * 64;
        int r = tid >> 2, f0 = (tid & 3) * 16;
        const float* xp = x + (size_t)(node0 + r) * NF + f0;
        float v[16];
        #pragma unroll
        for (int i = 0; i < 16; ++i) v[i] = xp[i];
        short8 p0, p1;
        #pragma unroll
        for (int i = 0; i < 8; ++i) { p0[i] = f2bs(v[i]); p1[i] = f2bs(v[8 + i]); }
        *(short8*)&xg[(size_t)(node0 + r) * NKF + f0] = p0;
        *(short8*)&xg[(size_t)(node0 + r) * NKF + f0 + 8] = p1;
        #pragma unroll
        for (int i = 0; i < 4; ++i)
            *(float4*)&Ts[r][f0 + i * 4] = *(const float4*)(v + i * 4);
        __syncthreads();
        int f = tid >> 2, nq0 = (tid & 3) * 16;
        int b = node0 >> 9, nloc = node0 & (NN - 1);
        bf16* xt = xT + (size_t)(b * NF + f) * NN + nloc + nq0;
        #pragma unroll
        for (int h = 0; h < 2; ++h) {
            short8 o;
            #pragma unroll
            for (int i = 0; i < 8; ++i) o[i] = f2bs(Ts[nq0 + h * 8 + i][f]);
            *(short8*)&xt[h * 8] = o;
        }
    } else {
        int q = bid - 2176;                        // 0..47
        int e = q / 3, kt = q % 3;
        int r = tid >> 2, o0 = (tid & 3) * 16;
        const float* wp = Wp + (size_t)e * (NKF * NF) + (size_t)(kt * 64 + r) * NF + o0;
        #pragma unroll
        for (int i = 0; i < 4; ++i)
            *(float4*)&Ts[r][o0 + i * 4] = *(const float4*)(wp + i * 4);
        __syncthreads();
        int o = tid >> 2, r0 = (tid & 3) * 16;
        bf16* bt = Bt + (size_t)(e * 64 + o) * NKF + kt * 64 + r0;
        #pragma unroll
        for (int h = 0; h < 2; ++h) {
            short8 w;
            #pragma unroll
            for (int i = 0; i < 8; ++i) w[i] = f2bs(Ts[r0 + h * 8 + i][o]);
            *(short8*)&bt[h * 8] = w;
        }
    }
}

// ---------------- k_ahat: Ah[b][n][m] = bf16(dn*dm*(relu(A)+I)) ------------
__global__ __launch_bounds__(256) void k_ahat(
    const float* __restrict__ A, const float* __restrict__ dis,
    bf16* __restrict__ Ah) {
    int tid = threadIdx.x;
    int row = blockIdx.x * 4 + (tid >> 6);         // global row 0..8191
    int m0 = (tid & 63) * 8;
    int b = row >> 9, n = row & (NN - 1);
    const float* db = dis + b * NN;
    float dn = db[n];
    const float* ap = A + (size_t)row * NN + m0;
    float4 a0 = *(const float4*)ap, a1 = *(const float4*)(ap + 4);
    float4 d0 = *(const float4*)(db + m0), d1 = *(const float4*)(db + m0 + 4);
    float av[8] = {a0.x, a0.y, a0.z, a0.w, a1.x, a1.y, a1.z, a1.w};
    float dm[8] = {d0.x, d0.y, d0.z, d0.w, d1.x, d1.y, d1.z, d1.w};
    short8 o;
    #pragma unroll
    for (int i = 0; i < 8; ++i) {
        float v = fmaxf(av[i], 0.f) + ((n == m0 + i) ? 1.f : 0.f);
        o[i] = f2bs(v * dn * dm[i]);
    }
    *(short8*)&Ah[(size_t)row * NN + m0] = o;
}

// ---------------- k_spmm (MFMA, K-chunk=128): C = Ah @ Bsrc^T --------------
// Ah rows: [n][m] bf16; Bsrc rows: [f][m] bf16 (xT PASS0, y1T PASS1)
// 4 K-iterations of 128 (4 swizzled [64][32] subtiles per operand per iter).
// PASS0: y1 = C -> xg[:,64:128] + y1T[b][f][n];  PASS1: y2 = 2C - x -> xg[:,128:192]
template <int PASS>
__global__ __launch_bounds__(256) void k_spmm(
    const short* __restrict__ Ah, const short* __restrict__ Bsrc,
    const float* __restrict__ x, bf16* __restrict__ xg, bf16* __restrict__ y1T) {
    __shared__ short As[4 * 2048];    // 4 subtiles [64][32], 16KB
    __shared__ short Xs[4 * 2048];    // 16KB
    __shared__ float Cs[64][66];      // 16.9KB
    int tid = threadIdx.x, lane = tid & 63, w = tid >> 6;
    int n0 = blockIdx.x * 64, b = blockIdx.y;
    const short* Ab = Ah + (size_t)b * NN * NN;
    const short* Xb = Bsrc + (size_t)b * NF * NN;

    int sr = tid >> 2;                  // staging row 0..63
    int p  = tid & 3;                   // stored chunk slot
    int cA = p ^ ((sr >> 1) & 3);       // logical chunk (XOR swizzle)

    int fr = lane & 15, ak = lane >> 4;

    f32x4 acc[4] = {};

    for (int kt = 0; kt < 4; ++kt) {    // K-chunk = 128
        __syncthreads();
        #pragma unroll
        for (int kc = 0; kc < 4; ++kc) {
            int col = kt * 128 + kc * 32 + cA * 8;
            gload16(Ab + (size_t)(n0 + sr) * NN + col, As + kc * 2048 + tid * 8);
            gload16(Xb + (size_t)sr * NN + col,        Xs + kc * 2048 + tid * 8);
        }
        __syncthreads();
        int rA = 16 * w + fr;
        int swA = (ak ^ ((rA >> 1) & 3)) * 8;
        #pragma unroll
        for (int kc = 0; kc < 4; ++kc) {
            short8 afr = *(const short8*)&As[kc * 2048 + rA * 32 + swA];
            #pragma unroll
            for (int j = 0; j < 4; ++j) {
                int colr = 16 * j + fr;
                short8 bfr = *(const short8*)&Xs[kc * 2048 + colr * 32 +
                                                 ((ak ^ ((colr >> 1) & 3)) * 8)];
                acc[j] = __builtin_amdgcn_mfma_f32_16x16x32_bf16(afr, bfr, acc[j], 0, 0, 0);
            }
        }
    }

    // C[16w + 4*(lane>>4) + r][16j + (lane&15)] = acc[j][r]
    #pragma unroll
    for (int j = 0; j < 4; ++j)
        #pragma unroll
        for (int r = 0; r < 4; ++r)
            Cs[16 * w + 4 * ak + r][16 * j + fr] = acc[j][r];
    __syncthreads();

    int nl = tid >> 2, f0 = (tid & 3) * 16;
    size_t node = (size_t)b * NN + n0 + nl;
    float cv[16];
    #pragma unroll
    for (int i = 0; i < 16; ++i) cv[i] = Cs[nl][f0 + i];
    if (PASS == 0) {
        short8 p0, p1;
        #pragma unroll
        for (int i = 0; i < 8; ++i) { p0[i] = f2bs(cv[i]); p1[i] = f2bs(cv[8 + i]); }
        *(short8*)&xg[node * NKF + 64 + f0] = p0;
        *(short8*)&xg[node * NKF + 64 + f0 + 8] = p1;
        int f = tid >> 2, nq0 = (tid & 3) * 16;
        bf16* yt = y1T + (size_t)(b * NF + f) * NN + n0 + nq0;
        #pragma unroll
        for (int h = 0; h < 2; ++h) {
            short8 o;
            #pragma unroll
            for (int i = 0; i < 8; ++i) o[i] = f2bs(Cs[nq0 + h * 8 + i][f]);
            *(short8*)&yt[h * 8] = o;
        }
    } else {
        const float* xp = x + node * NF + f0;
        short8 p0, p1;
        #pragma unroll
        for (int i = 0; i < 8; ++i) {
            p0[i] = f2bs(2.f * cv[i] - xp[i]);
            p1[i] = f2bs(2.f * cv[8 + i] - xp[8 + i]);
        }
        *(short8*)&xg[node * NKF + 128 + f0] = p0;
        *(short8*)&xg[node * NKF + 128 + f0 + 8] = p1;
    }
}

// ---------------- k_gemm: t = Xg @ Bt^T (bf16 MFMA, 128x128 tile) ----------
// Xg: [8192][192] bf16, Bt: [1024][192] bf16, t: [8192][1024] bf16  (R7-verified)
__global__ __launch_bounds__(256) void k_gemm(
    const short* __restrict__ xg, const short* __restrict__ Bt,
    bf16* __restrict__ t) {
    __shared__ short As[128 * 32];
    __shared__ short Bs[128 * 32];
    int tid = threadIdx.x;
    int lane = tid & 63;
    int w = tid >> 6;
    int n0 = blockIdx.x * 128;
    int c0 = blockIdx.y * 128;

    int rA0 = tid >> 2;
    int p   = tid & 3;
    int cA  = p ^ ((rA0 >> 1) & 3);

    int fr = lane & 15;
    int fc = ((lane >> 4) ^ ((fr >> 1) & 3)) * 8;

    f32x4 acc[4][4] = {};

    for (int kt = 0; kt < 6; ++kt) {
        __syncthreads();
        gload16(xg + (size_t)(n0 + rA0) * NKF + kt * 32 + cA * 8, As + tid * 8);
        gload16(xg + (size_t)(n0 + rA0 + 64) * NKF + kt * 32 + cA * 8, As + 2048 + tid * 8);
        gload16(Bt + (size_t)(c0 + rA0) * NKF + kt * 32 + cA * 8, Bs + tid * 8);
        gload16(Bt + (size_t)(c0 + rA0 + 64) * NKF + kt * 32 + cA * 8, Bs + 2048 + tid * 8);
        __syncthreads();

        int wr = w >> 1, wc = w & 1;
        short8 a[4], bfr[4];
        #pragma unroll
        for (int i = 0; i < 4; ++i)
            a[i] = *(const short8*)&As[(wr * 64 + i * 16 + fr) * 32 + fc];
        #pragma unroll
        for (int j = 0; j < 4; ++j)
            bfr[j] = *(const short8*)&Bs[(wc * 64 + j * 16 + fr) * 32 + fc];
        #pragma unroll
        for (int i = 0; i < 4; ++i)
            #pragma unroll
            for (int j = 0; j < 4; ++j)
                acc[i][j] = __builtin_amdgcn_mfma_f32_16x16x32_bf16(a[i], bfr[j], acc[i][j], 0, 0, 0);
    }

    int wr = w >> 1, wc = w & 1;
    #pragma unroll
    for (int i = 0; i < 4; ++i) {
        #pragma unroll
        for (int j = 0; j < 4; ++j) {
            #pragma unroll
            for (int r = 0; r < 4; ++r) {
                int m = n0 + wr * 64 + i * 16 + (lane >> 4) * 4 + r;
                int cc = c0 + wc * 64 + j * 16 + (lane & 15);
                t[(size_t)m * 1024 + cc] = __float2bfloat16(acc[i][j][r]);
            }
        }
    }
}

// ---------------- k_reduce: out = sum_e emb*(t + bias) ---------------------
__global__ void k_reduce(const bf16* __restrict__ t, const float* __restrict__ emb,
                         const float* __restrict__ bp, float* __restrict__ out) {
    int gid = blockIdx.x * 256 + threadIdx.x;      // 0..524287
    int node = gid >> 6, o = gid & 63;
    float s = 0.f;
    #pragma unroll
    for (int e = 0; e < NE; ++e) {
        float tv = __bfloat162float(t[(size_t)node * 1024 + e * 64 + o]);
        s = fmaf(emb[(size_t)node * NE + e], tv + bp[e * 64 + o], s);
    }
    out[gid] = s;
}

extern "C" void kernel_launch(void* const* d_in, const int* in_sizes, int n_in,
                              void* d_out, int out_size, void* d_ws, size_t ws_size,
                              hipStream_t stream) {
    const float* x   = (const float*)d_in[0];   // [16,512,64]
    const float* emb = (const float*)d_in[1];   // [16,512,16]
    const float* A   = (const float*)d_in[2];   // [16,512,512]
    const float* Wp  = (const float*)d_in[3];   // [16,3,64,64]
    const float* bp  = (const float*)d_in[4];   // [16,64]
    float* out = (float*)d_out;                 // [16,512,64]

    float* ws  = (float*)d_ws;
    float* dis = ws;                                  // 8192 f32
    bf16*  xT  = (bf16*)(ws + 8192);                  // 16*64*512 bf16
    bf16*  y1T = (bf16*)(ws + 270336);                // same
    bf16*  xg  = (bf16*)(ws + 532480);                // 8192*192 bf16
    bf16*  Bt  = (bf16*)(ws + 1318912);               // 1024*192 bf16
    bf16*  Ah  = (bf16*)(ws + 1417216);               // 16*512*512 bf16
    bf16*  t   = (bf16*)(ws + 3514368);               // 8192*1024 bf16
    // ws end: 7708672 f32 = 30.8 MB

    k_pre<<<2224, 256, 0, stream>>>(A, x, Wp, dis, xg, xT, Bt);
    k_ahat<<<2048, 256, 0, stream>>>(A, dis, Ah);
    dim3 g2(NN / 64, NB);
    k_spmm<0><<<g2, 256, 0, stream>>>((const short*)Ah, (const short*)xT, x, xg, y1T);
    k_spmm<1><<<g2, 256, 0, stream>>>((const short*)Ah, (const short*)y1T, x, xg, y1T);
    dim3 gg(NNODE / 128, 8);
    k_gemm<<<gg, 256, 0, stream>>>((const short*)xg, (const short*)Bt, t);
    k_reduce<<<NNODE * NF / 256, 256, 0, stream>>>(t, emb, bp, out);
}